// Round 10
// baseline (88.048 us; speedup 1.0000x reference)
//
#include <hip/hip_runtime.h>
#include <math.h>

#define TPB       256
#define KA        16                 // queries per thread (register blocking)
#define QPB       (TPB * KA)         // 4096 queries per block = whole query set
#define C_CHUNKS  32                 // B-set split across blocks
#define CPTS      128                // points per chunk (4096/32)
#define CHUNK_F   (CPTS * 4)         // 512 floats per chunk (SoA: X,Y,Z,W each 128)

typedef float v2f __attribute__((ext_vector_type(2)));

// prep: transform src->gts, pack both sets into chunked SoA:
// per (b, chunk): [X[128] | Y[128] | Z[128] | W[128]], W = |p|^2.
// Also zeroes d_out.
__global__ __launch_bounds__(TPB) void prep_kernel(
    const float* __restrict__ recon,   // B*M*3
    const float* __restrict__ src,     // B*N*3
    const float* __restrict__ T,       // B*16
    float* __restrict__ preds_soa,     // B*M*4
    float* __restrict__ gts_soa,       // B*N*4
    float* __restrict__ out, int out_n,
    int B, int N, int M)
{
    int idx = blockIdx.x * TPB + threadIdx.x;
    if (idx < out_n) out[idx] = 0.0f;
    int totG = B * N;
    int totP = B * M;
    if (idx < totG) {
        int b = idx / N, n = idx - b * N;
        const float* Tb = T + b * 16;
        float x = src[3*idx + 0], y = src[3*idx + 1], z = src[3*idx + 2];
        float gx = fmaf(Tb[0], x, fmaf(Tb[1], y, fmaf(Tb[2],  z, Tb[3])));
        float gy = fmaf(Tb[4], x, fmaf(Tb[5], y, fmaf(Tb[6],  z, Tb[7])));
        float gz = fmaf(Tb[8], x, fmaf(Tb[9], y, fmaf(Tb[10], z, Tb[11])));
        size_t base = ((size_t)b * (N / CPTS) + (n >> 7)) * CHUNK_F + (n & 127);
        gts_soa[base      ] = gx;
        gts_soa[base + 128] = gy;
        gts_soa[base + 256] = gz;
        gts_soa[base + 384] = fmaf(gx, gx, fmaf(gy, gy, gz * gz));
    } else if (idx - totG < totP) {
        int k = idx - totG;
        int b = k / M, m = k - b * M;
        float x = recon[3*k + 0], y = recon[3*k + 1], z = recon[3*k + 2];
        size_t base = ((size_t)b * (M / CPTS) + (m >> 7)) * CHUNK_F + (m & 127);
        preds_soa[base      ] = x;
        preds_soa[base + 128] = y;
        preds_soa[base + 256] = z;
        preds_soa[base + 384] = fmaf(x, x, fmaf(y, y, z * z));
    }
}

// KA=16: each block handles ALL 4096 queries of (b, dir) against one 128-pt chunk.
// Per K-iter per wave: 8 ds_read_b64 feed 16 queries x 4 points -> LDS instr
// per distance halved vs KA=8 (the R9 co-pipe limiter). 2 waves/SIMD.
// dir 0: A=gts (N queries), B=preds.  dir 1: A=preds (M queries), B=gts.
__global__ __launch_bounds__(TPB, 2) void chamfer_kernel(
    const float* __restrict__ gts_soa,
    const float* __restrict__ preds_soa,
    float* __restrict__ partial,       // [C_CHUNKS][GQ]
    int B, int N, int M, int GQ)
{
    __shared__ __align__(16) float sL[CHUNK_F];   // one B-chunk, SoA (2 KiB)

    const int dir = blockIdx.z;
    const int b   = blockIdx.y;
    const int c   = blockIdx.x;        // grid.x == C_CHUNKS

    const int NA  = (dir == 0) ? N : M;
    const int NB_ = (dir == 0) ? M : N;

    const float* __restrict__ Asoa = (dir == 0) ? gts_soa : preds_soa;
    const float* __restrict__ Bsoa = (dir == 0) ? preds_soa : gts_soa;
    const int gq_base = ((dir == 0) ? 0 : B * N) + b * NA;

    // Stage this chunk (2 KiB, linear) into LDS: 128 threads x 16B.
    {
        const float4* gsrc = (const float4*)(Bsoa + ((size_t)b * (NB_ / CPTS) + c) * CHUNK_F);
        if (threadIdx.x < CPTS) ((float4*)sL)[threadIdx.x] = gsrc[threadIdx.x];
    }
    __syncthreads();

    // Load KA queries from SoA (coalesced per component); pack -2*comp pairs.
    float aw[KA], mA[KA], mB[KA];
    v2f A2X[KA], A2Y[KA], A2Z[KA];
    const int qi0 = (int)threadIdx.x;
    #pragma unroll
    for (int k = 0; k < KA; ++k) {
        int q = qi0 + k * TPB;                       // < NA always (QPB == NA)
        const float* ab = Asoa + ((size_t)b * (NA / CPTS) + (q >> 7)) * CHUNK_F + (q & 127);
        float ax = ab[0], ay = ab[128], az = ab[256];
        aw[k] = ab[384];
        float tx = -2.0f * ax, ty = -2.0f * ay, tz = -2.0f * az;
        A2X[k].x = tx; A2X[k].y = tx;
        A2Y[k].x = ty; A2Y[k].y = ty;
        A2Z[k].x = tz; A2Z[k].y = tz;
        mA[k] = INFINITY; mB[k] = INFINITY;
    }

    const v2f* sX = (const v2f*)(sL +   0);   // 64 pairs
    const v2f* sY = (const v2f*)(sL + 128);
    const v2f* sZ = (const v2f*)(sL + 256);
    const v2f* sW = (const v2f*)(sL + 384);

    // 32 iterations x 4 points; 32 independent FMA chains (16 k x 2).
    for (int jj = 0; jj < CPTS / 2; jj += 2) {
        v2f x0 = sX[jj],   y0 = sY[jj],   z0 = sZ[jj],   w0 = sW[jj];
        v2f x1 = sX[jj+1], y1 = sY[jj+1], z1 = sZ[jj+1], w1 = sW[jj+1];
        #pragma unroll
        for (int k = 0; k < KA; ++k) {
            v2f d0, d1;
            asm("v_pk_fma_f32 %0, %1, %2, %3" : "=v"(d0) : "v"(A2Z[k]), "v"(z0), "v"(w0));
            asm("v_pk_fma_f32 %0, %1, %2, %0" : "+v"(d0) : "v"(A2Y[k]), "v"(y0));
            asm("v_pk_fma_f32 %0, %1, %2, %0" : "+v"(d0) : "v"(A2X[k]), "v"(x0));
            asm("v_pk_fma_f32 %0, %1, %2, %3" : "=v"(d1) : "v"(A2Z[k]), "v"(z1), "v"(w1));
            asm("v_pk_fma_f32 %0, %1, %2, %0" : "+v"(d1) : "v"(A2Y[k]), "v"(y1));
            asm("v_pk_fma_f32 %0, %1, %2, %0" : "+v"(d1) : "v"(A2X[k]), "v"(x1));
            mA[k] = fminf(fminf(mA[k], d0.x), d0.y);   // -> v_min3_f32
            mB[k] = fminf(fminf(mB[k], d1.x), d1.y);
        }
    }

    // Coalesced partial writes (aw added back after the min).
    #pragma unroll
    for (int k = 0; k < KA; ++k) {
        int q = qi0 + k * TPB;
        partial[(size_t)c * GQ + gq_base + q] = aw[k] + fminf(mA[k], mB[k]);
    }
}

// Combine: per-query min over chunks, then global sum.
__global__ __launch_bounds__(TPB) void reduce_kernel(
    const float* __restrict__ partial, float* __restrict__ out, int GQ)
{
    int q = blockIdx.x * TPB + threadIdx.x;
    float m = 0.0f;
    if (q < GQ) {
        m = partial[q];
        #pragma unroll
        for (int c = 1; c < C_CHUNKS; ++c)
            m = fminf(m, partial[(size_t)c * GQ + q]);
    }
    #pragma unroll
    for (int off = 32; off > 0; off >>= 1) m += __shfl_down(m, off);
    __shared__ float red[TPB / 64];
    if ((threadIdx.x & 63) == 0) red[threadIdx.x >> 6] = m;
    __syncthreads();
    if (threadIdx.x == 0) {
        float s = 0.0f;
        #pragma unroll
        for (int w = 0; w < TPB / 64; ++w) s += red[w];
        atomicAdd(out, s);
    }
}

extern "C" void kernel_launch(void* const* d_in, const int* in_sizes, int n_in,
                              void* d_out, int out_size, void* d_ws, size_t ws_size,
                              hipStream_t stream)
{
    const float* recon = (const float*)d_in[0];   // (B, M, 3)
    const float* src   = (const float*)d_in[1];   // (B, N, 3)
    const float* T     = (const float*)d_in[2];   // (B, 4, 4)

    const int B = in_sizes[2] / 16;
    const int M = in_sizes[0] / (B * 3);
    const int N = in_sizes[1] / (B * 3);
    const int GQ = B * (N + M);

    float* preds_soa = (float*)d_ws;                            // B*M*4 floats
    float* gts_soa   = preds_soa + (size_t)B * M * 4;           // B*N*4 floats
    float* partial   = gts_soa + (size_t)B * N * 4;             // C_CHUNKS * GQ
    float* out       = (float*)d_out;

    prep_kernel<<<dim3((GQ + TPB - 1) / TPB), dim3(TPB), 0, stream>>>(
        recon, src, T, preds_soa, gts_soa, out, out_size, B, N, M);

    dim3 grid(C_CHUNKS, B, 2);
    chamfer_kernel<<<grid, dim3(TPB), 0, stream>>>(gts_soa, preds_soa, partial, B, N, M, GQ);

    reduce_kernel<<<dim3((GQ + TPB - 1) / TPB), dim3(TPB), 0, stream>>>(partial, out, GQ);
}